// Round 1
// baseline (277.155 us; speedup 1.0000x reference)
//
#include <hip/hip_runtime.h>
#include <hip/hip_bf16.h>

// MHA forward: bf16 MFMA everywhere (fp32 accum, fp32 softmax).
// Pipeline: transpose weights -> 3 proj GEMMs -> V transpose -> flash attn -> out GEMM.

typedef __bf16 bf16;
typedef __bf16 bf16x8 __attribute__((ext_vector_type(8)));
typedef __bf16 bf16x4 __attribute__((ext_vector_type(4)));
typedef float  f32x4  __attribute__((ext_vector_type(4)));

#define MFMA16(a, b, c) __builtin_amdgcn_mfma_f32_16x16x32_bf16((a), (b), (c), 0, 0, 0)

// ---------------- weight transpose: W[k][n] fp32 -> Wt[n][k] bf16 ----------------
__global__ __launch_bounds__(256) void k_transpose_w(const float* __restrict__ W,
                                                     bf16* __restrict__ Wt) {
    __shared__ bf16 t[64][65];
    const int n0 = blockIdx.x * 64, k0 = blockIdx.y * 64;
    for (int i = 0; i < 16; ++i) {
        int idx = threadIdx.x + i * 256, r = idx >> 6, c = idx & 63;
        t[r][c] = (bf16)W[(size_t)(k0 + r) * 1024 + n0 + c];
    }
    __syncthreads();
    for (int i = 0; i < 16; ++i) {
        int idx = threadIdx.x + i * 256, r = idx >> 6, c = idx & 63;
        Wt[(size_t)(n0 + r) * 1024 + k0 + c] = t[c][r];
    }
}

// ---------------- V transpose: V[bh][s][d] bf16 -> Vt[bh][d][s] bf16 ----------------
__global__ __launch_bounds__(256) void k_transpose_v(const bf16* __restrict__ V,
                                                     bf16* __restrict__ Vt) {
    __shared__ bf16 t[64][65];
    const int s0 = blockIdx.x * 64, bh = blockIdx.y;
    for (int i = 0; i < 16; ++i) {
        int idx = threadIdx.x + i * 256, r = idx >> 6, c = idx & 63;
        t[r][c] = V[((size_t)bh * 2048 + s0 + r) * 64 + c];
    }
    __syncthreads();
    for (int i = 0; i < 16; ++i) {
        int idx = threadIdx.x + i * 256, r = idx >> 6, c = idx & 63;
        Vt[((size_t)bh * 64 + r) * 2048 + s0 + c] = t[c][r];
    }
}

// ---------------- GEMM: C = A @ Bt^T + bias ----------------
// A: [M][K] (fp32 if !A_BF16 else bf16), Bt: [N][K] bf16.
// OUT_MODE 0: bf16 head layout [b][h][s][d] (S=2048, dk=64, H=16)
// OUT_MODE 1: fp32 flat [M][N]
template <int A_BF16, int OUT_MODE>
__global__ __launch_bounds__(256) void k_gemm(const void* __restrict__ Ap,
                                              const bf16* __restrict__ Bt,
                                              const float* __restrict__ bias,
                                              void* __restrict__ Cp,
                                              int M, int N, int K) {
    __shared__ bf16 As[128][72];
    __shared__ bf16 Bs[128][72];
    const int tid = threadIdx.x;
    const int wid = tid >> 6, lane = tid & 63, lg = lane >> 4, lm = lane & 15;
    const int wr = wid >> 1, wc = wid & 1;
    const int m0 = blockIdx.y * 128, n0 = blockIdx.x * 128;

    f32x4 acc[4][4] = {};

    const int nkt = K >> 6;
    for (int kt = 0; kt < nkt; ++kt) {
        const int k0 = kt << 6;
        __syncthreads();
        if constexpr (A_BF16) {
            const bf16* A = (const bf16*)Ap;
            for (int p = 0; p < 4; ++p) {
                int idx = tid + (p << 8);
                int r = idx >> 3, c = (idx & 7) << 3;
                *(bf16x8*)&As[r][c] = *(const bf16x8*)&A[(size_t)(m0 + r) * K + k0 + c];
            }
        } else {
            const float* A = (const float*)Ap;
            for (int p = 0; p < 8; ++p) {
                int idx = tid + (p << 8);
                int r = idx >> 4, c = (idx & 15) << 2;
                float4 v = *(const float4*)&A[(size_t)(m0 + r) * K + k0 + c];
                bf16x4 w = {(bf16)v.x, (bf16)v.y, (bf16)v.z, (bf16)v.w};
                *(bf16x4*)&As[r][c] = w;
            }
        }
        for (int p = 0; p < 4; ++p) {
            int idx = tid + (p << 8);
            int r = idx >> 3, c = (idx & 7) << 3;
            *(bf16x8*)&Bs[r][c] = *(const bf16x8*)&Bt[(size_t)(n0 + r) * K + k0 + c];
        }
        __syncthreads();
        for (int kk = 0; kk < 2; ++kk) {
            bf16x8 a[4], b[4];
            for (int i = 0; i < 4; ++i)
                a[i] = *(const bf16x8*)&As[wr * 64 + i * 16 + lm][kk * 32 + lg * 8];
            for (int j = 0; j < 4; ++j)
                b[j] = *(const bf16x8*)&Bs[wc * 64 + j * 16 + lm][kk * 32 + lg * 8];
            for (int i = 0; i < 4; ++i)
                for (int j = 0; j < 4; ++j)
                    acc[i][j] = MFMA16(a[i], b[j], acc[i][j]);
        }
    }

    for (int i = 0; i < 4; ++i) {
        for (int j = 0; j < 4; ++j) {
            int col = n0 + wc * 64 + j * 16 + lm;
            float bv = bias[col];
            for (int q = 0; q < 4; ++q) {
                int row = m0 + wr * 64 + i * 16 + lg * 4 + q;
                float val = acc[i][j][q] + bv;
                if constexpr (OUT_MODE == 0) {
                    int bb = row >> 11, s = row & 2047, h = col >> 6, d = col & 63;
                    ((bf16*)Cp)[(((size_t)bb * 16 + h) * 2048 + s) * 64 + d] = (bf16)val;
                } else {
                    ((float*)Cp)[(size_t)row * N + col] = val;
                }
            }
        }
    }
}

// ---------------- flash attention ----------------
// Q,K: [bh][2048][64] bf16; Vt: [bh][64][2048] bf16; Out: [b][s][h*64+d] bf16
__global__ __launch_bounds__(256) void k_attn(const bf16* __restrict__ Q,
                                              const bf16* __restrict__ Kb,
                                              const bf16* __restrict__ Vt,
                                              bf16* __restrict__ Out) {
    __shared__ bf16 Qs[128][72];
    __shared__ bf16 Ks[64][72];
    __shared__ bf16 Vs[64][72];  // Vs[d][s_k]
    __shared__ bf16 Ps[128][72];
    const int tid = threadIdx.x;
    const int wid = tid >> 6, lane = tid & 63, lg = lane >> 4, lm = lane & 15;
    const int bh = blockIdx.y;
    const int q0 = blockIdx.x * 128;
    const int wm = wid * 32;
    const size_t qk_base = (size_t)bh * 2048 * 64;
    const size_t vt_base = (size_t)bh * 64 * 2048;

    for (int p = 0; p < 4; ++p) {
        int idx = tid + (p << 8);
        int r = idx >> 3, c = (idx & 7) << 3;
        *(bf16x8*)&Qs[r][c] = *(const bf16x8*)&Q[qk_base + (size_t)(q0 + r) * 64 + c];
    }

    f32x4 O[2][4] = {};
    float mst[2][4], lst[2][4];
    for (int i = 0; i < 2; ++i)
        for (int q = 0; q < 4; ++q) { mst[i][q] = -1e30f; lst[i][q] = 0.f; }

    for (int kt = 0; kt < 32; ++kt) {
        __syncthreads();  // protect Ks/Vs/Ps reuse; also covers initial Qs staging
        for (int p = 0; p < 2; ++p) {
            int idx = tid + (p << 8);
            int r = idx >> 3, c = (idx & 7) << 3;
            *(bf16x8*)&Ks[r][c] = *(const bf16x8*)&Kb[qk_base + (size_t)(kt * 64 + r) * 64 + c];
            *(bf16x8*)&Vs[r][c] = *(const bf16x8*)&Vt[vt_base + (size_t)r * 2048 + kt * 64 + c];
        }
        __syncthreads();

        // QK^T -> sacc[fm][fn], rows 32 per wave, cols 64
        f32x4 sacc[2][4] = {};
        for (int kk = 0; kk < 2; ++kk) {
            bf16x8 a[2], b[4];
            for (int i = 0; i < 2; ++i)
                a[i] = *(const bf16x8*)&Qs[wm + i * 16 + lm][kk * 32 + lg * 8];
            for (int j = 0; j < 4; ++j)
                b[j] = *(const bf16x8*)&Ks[j * 16 + lm][kk * 32 + lg * 8];
            for (int i = 0; i < 2; ++i)
                for (int j = 0; j < 4; ++j)
                    sacc[i][j] = MFMA16(a[i], b[j], sacc[i][j]);
        }
        for (int i = 0; i < 2; ++i)
            for (int j = 0; j < 4; ++j)
                for (int q = 0; q < 4; ++q) sacc[i][j][q] *= 0.125f;  // 1/sqrt(64)

        // online softmax (fp32). Row r of frag: lanes lg==r>>2 hold its 16 cols.
        for (int i = 0; i < 2; ++i) {
            for (int q = 0; q < 4; ++q) {
                float mx = fmaxf(fmaxf(sacc[i][0][q], sacc[i][1][q]),
                                 fmaxf(sacc[i][2][q], sacc[i][3][q]));
                for (int m = 1; m < 16; m <<= 1) mx = fmaxf(mx, __shfl_xor(mx, m, 64));
                float mnew = fmaxf(mst[i][q], mx);
                float corr = __expf(mst[i][q] - mnew);
                float pv[4];
                float rs = 0.f;
                for (int j = 0; j < 4; ++j) {
                    float p = __expf(sacc[i][j][q] - mnew);
                    pv[j] = p;
                    rs += p;
                }
                for (int m = 1; m < 16; m <<= 1) rs += __shfl_xor(rs, m, 64);
                mst[i][q] = mnew;
                lst[i][q] = lst[i][q] * corr + rs;
                for (int d = 0; d < 4; ++d) O[i][d][q] *= corr;
                int prow = wm + i * 16 + lg * 4 + q;
                for (int j = 0; j < 4; ++j) Ps[prow][j * 16 + lm] = (bf16)pv[j];
            }
        }
        __syncthreads();

        // PV: O += P @ V   (B-operand from Vs[d][s_k], k-contiguous)
        for (int ks = 0; ks < 2; ++ks) {
            bf16x8 a[2], b[4];
            for (int i = 0; i < 2; ++i)
                a[i] = *(const bf16x8*)&Ps[wm + i * 16 + lm][ks * 32 + lg * 8];
            for (int j = 0; j < 4; ++j)
                b[j] = *(const bf16x8*)&Vs[j * 16 + lm][ks * 32 + lg * 8];
            for (int i = 0; i < 2; ++i)
                for (int j = 0; j < 4; ++j)
                    O[i][j] = MFMA16(a[i], b[j], O[i][j]);
        }
    }

    const int bb = bh >> 4, h = bh & 15;
    for (int i = 0; i < 2; ++i) {
        for (int q = 0; q < 4; ++q) {
            float inv = 1.f / lst[i][q];
            int row = q0 + wm + i * 16 + lg * 4 + q;
            for (int j = 0; j < 4; ++j) {
                int d = j * 16 + lm;
                Out[((size_t)bb * 2048 + row) * 1024 + h * 64 + d] = (bf16)(O[i][j][q] * inv);
            }
        }
    }
}

extern "C" void kernel_launch(void* const* d_in, const int* in_sizes, int n_in,
                              void* d_out, int out_size, void* d_ws, size_t ws_size,
                              hipStream_t stream) {
    const float* q  = (const float*)d_in[0];
    const float* k  = (const float*)d_in[1];
    const float* v  = (const float*)d_in[2];
    const float* Wq = (const float*)d_in[3];
    const float* bq = (const float*)d_in[4];
    const float* Wk = (const float*)d_in[5];
    const float* bk = (const float*)d_in[6];
    const float* Wv = (const float*)d_in[7];
    const float* bv = (const float*)d_in[8];
    const float* Wo = (const float*)d_in[9];
    const float* bo = (const float*)d_in[10];

    char* ws = (char*)d_ws;
    // workspace slots (34 MB total, Wt slot reused per weight, AOb reuses Vb)
    bf16* Wt  = (bf16*)(ws + 0);                    // 2 MB, reused for each W^T
    bf16* Qb  = (bf16*)(ws + (2ull << 20));         // 8 MB  [b][h][s][d]
    bf16* Kb  = (bf16*)(ws + (10ull << 20));        // 8 MB  [b][h][s][d]
    bf16* Vb  = (bf16*)(ws + (18ull << 20));        // 8 MB  [b][h][s][d]; reused as AOb
    bf16* Vtb = (bf16*)(ws + (26ull << 20));        // 8 MB  [b][h][d][s]
    bf16* AOb = Vb;                                  // attn out [b][s][h*64+d]

    const dim3 twg(16, 16), gg(8, 32), blk(256);

    // Q projection
    k_transpose_w<<<twg, blk, 0, stream>>>(Wq, Wt);
    k_gemm<0, 0><<<gg, blk, 0, stream>>>((const void*)q, Wt, bq, (void*)Qb, 4096, 1024, 1024);
    // K projection
    k_transpose_w<<<twg, blk, 0, stream>>>(Wk, Wt);
    k_gemm<0, 0><<<gg, blk, 0, stream>>>((const void*)k, Wt, bk, (void*)Kb, 4096, 1024, 1024);
    // V projection
    k_transpose_w<<<twg, blk, 0, stream>>>(Wv, Wt);
    k_gemm<0, 0><<<gg, blk, 0, stream>>>((const void*)v, Wt, bv, (void*)Vb, 4096, 1024, 1024);
    // V -> Vt
    k_transpose_v<<<dim3(32, 32), blk, 0, stream>>>(Vb, Vtb);
    // Wo^T (before attn overwrites nothing it needs; Wt slot free now)
    k_transpose_w<<<twg, blk, 0, stream>>>(Wo, Wt);
    // attention (AOb aliases Vb; attn reads Qb/Kb/Vtb only)
    k_attn<<<dim3(16, 32), blk, 0, stream>>>(Qb, Kb, Vtb, AOb);
    // output projection -> fp32 d_out
    k_gemm<1, 1><<<gg, blk, 0, stream>>>((const void*)AOb, Wt, bo, d_out, 4096, 1024, 1024);
}

// Round 3
// 209.283 us; speedup vs baseline: 1.3243x; 1.3243x over previous
//
#include <hip/hip_runtime.h>
#include <hip/hip_bf16.h>
#include <stdint.h>

typedef __bf16 bf16;
typedef __bf16 bf16x8 __attribute__((ext_vector_type(8)));
typedef __bf16 bf16x4 __attribute__((ext_vector_type(4)));
typedef float  f32x4  __attribute__((ext_vector_type(4)));
typedef float  f32x16 __attribute__((ext_vector_type(16)));
typedef uint32_t u32;

#define MFMA16(a,b,c) __builtin_amdgcn_mfma_f32_16x16x32_bf16((a),(b),(c),0,0,0)
#define MFMA32(a,b,c) __builtin_amdgcn_mfma_f32_32x32x16_bf16((a),(b),(c),0,0,0)

// 0.125 (1/sqrt(64)) * log2(e): folded into Wq/bq so softmax runs in exp2 domain.
#define QSCL 0.1803368801111204f

// ---------- helpers ----------
__device__ __forceinline__ u32 sx32(u32 x) {  // value from lane^32 (unambiguous)
    return (u32)__shfl_xor((int)x, 32, 64);
}
__device__ __forceinline__ float swapred_max(float v) {
    return fmaxf(v, __builtin_bit_cast(float, sx32(__builtin_bit_cast(u32, v))));
}
__device__ __forceinline__ float swapred_sum(float v) {
    return v + __builtin_bit_cast(float, sx32(__builtin_bit_cast(u32, v)));
}
__device__ __forceinline__ u32 pkbf(float lo, float hi) {
    union { bf16 h[2]; u32 u; } un;
    un.h[0] = (bf16)lo; un.h[1] = (bf16)hi;
    return un.u;
}
// p[16] = exp'd scores for one 32-row K-block; lane (lm,hi) holds k_local(r) =
// (r&3) + 8*(r>>2) + 4*hi for col q=lm. Produce PV B-frags f0 (k=0..15) and
// f1 (k=16..31): lane needs k = 16*ks + hi*8 + j (j=0..7) at col q=lm.
__device__ __forceinline__ void pack_frags(const float* p, int hi, bf16x8& f0, bf16x8& f1) {
    u32 k01 = pkbf(p[0],  p[1]),  k23 = pkbf(p[2],  p[3]);
    u32 k45 = pkbf(p[4],  p[5]),  k67 = pkbf(p[6],  p[7]);
    u32 k89 = pkbf(p[8],  p[9]),  kab = pkbf(p[10], p[11]);
    u32 kcd = pkbf(p[12], p[13]), kef = pkbf(p[14], p[15]);
    u32 x01 = sx32(k01), x23 = sx32(k23), x45 = sx32(k45), x67 = sx32(k67);
    u32 x89 = sx32(k89), xab = sx32(kab), xcd = sx32(kcd), xef = sx32(kef);
    union { u32 w[4]; bf16x8 v; } u0, u1;
    u0.w[0] = hi ? x45 : k01;  u0.w[1] = hi ? x67 : k23;
    u0.w[2] = hi ? k45 : x01;  u0.w[3] = hi ? k67 : x23;
    u1.w[0] = hi ? xcd : k89;  u1.w[1] = hi ? xef : kab;
    u1.w[2] = hi ? kcd : x89;  u1.w[3] = hi ? kef : xab;
    f0 = u0.v; f1 = u1.v;
}

// ---------------- fp32 -> bf16 converts ----------------
__global__ __launch_bounds__(256) void k_cvt3(const float* __restrict__ a, const float* __restrict__ b,
                                              const float* __restrict__ c,
                                              bf16* __restrict__ x, bf16* __restrict__ y,
                                              bf16* __restrict__ z) {
    int i = blockIdx.x * 256 + threadIdx.x;          // vec4 index, 3 * 2^20 total
    int t = i >> 20;
    int r = (i & 1048575) << 2;
    const float* s = (t == 0) ? a : ((t == 1) ? b : c);
    bf16* d = (t == 0) ? x : ((t == 1) ? y : z);
    float4 v = *(const float4*)&s[r];
    bf16x4 w = {(bf16)v.x, (bf16)v.y, (bf16)v.z, (bf16)v.w};
    *(bf16x4*)&d[r] = w;
}
__global__ __launch_bounds__(256) void k_cvt1(const float* __restrict__ s, bf16* __restrict__ d) {
    int r = (blockIdx.x * 256 + threadIdx.x) << 2;
    float4 v = *(const float4*)&s[r];
    bf16x4 w = {(bf16)v.x, (bf16)v.y, (bf16)v.z, (bf16)v.w};
    *(bf16x4*)&d[r] = w;
}

// ---------------- weight transpose: W[k][n] fp32 -> Wt[n][k] bf16 (* scale) ----------------
__global__ __launch_bounds__(256) void k_transpose_w(const float* __restrict__ W,
                                                     bf16* __restrict__ Wt, float scale) {
    __shared__ bf16 t[64][65];
    const int n0 = blockIdx.x * 64, k0 = blockIdx.y * 64;
    for (int i = 0; i < 16; ++i) {
        int idx = threadIdx.x + i * 256, r = idx >> 6, c = idx & 63;
        t[r][c] = (bf16)(W[(size_t)(k0 + r) * 1024 + n0 + c] * scale);
    }
    __syncthreads();
    for (int i = 0; i < 16; ++i) {
        int idx = threadIdx.x + i * 256, r = idx >> 6, c = idx & 63;
        Wt[(size_t)(n0 + r) * 1024 + k0 + c] = t[c][r];
    }
}

// ---------------- V transpose: V[bh][s][d] -> Vt[bh][d][s] ----------------
__global__ __launch_bounds__(256) void k_transpose_v(const bf16* __restrict__ V,
                                                     bf16* __restrict__ Vt) {
    __shared__ bf16 t[64][65];
    const int s0 = blockIdx.x * 64, bh = blockIdx.y;
    for (int i = 0; i < 16; ++i) {
        int idx = threadIdx.x + i * 256, r = idx >> 6, c = idx & 63;
        t[r][c] = V[((size_t)bh * 2048 + s0 + r) * 64 + c];
    }
    __syncthreads();
    for (int i = 0; i < 16; ++i) {
        int idx = threadIdx.x + i * 256, r = idx >> 6, c = idx & 63;
        Vt[((size_t)bh * 64 + r) * 2048 + s0 + c] = t[c][r];
    }
}

// ---------------- GEMM tile body: C[128x128] = A[128x1024] @ Bt[128x1024]^T + bias ----------------
// M=4096, N=1024, K=1024 fixed. global_load_lds width-16 staging, linear [128][64] LDS (m97 pattern).
__device__ __forceinline__ void gemm_tile(const bf16* __restrict__ A, const bf16* __restrict__ Bt,
                                          const float* __restrict__ bias, float bscale,
                                          void* __restrict__ Cp, int out_mode, int m0, int n0,
                                          bf16 (*As)[64], bf16 (*Bs)[64]) {
    const int tid = threadIdx.x;
    const int wid = tid >> 6, lane = tid & 63, lg = lane >> 4, lm = lane & 15;
    const int wr = wid >> 1, wc = wid & 1;
    const int grow = tid >> 3, gcol = (tid & 7) << 3;

    f32x4 acc[4][4] = {};

    for (int kt = 0; kt < 16; ++kt) {
        const int k0 = kt << 6;
        __syncthreads();
#pragma unroll
        for (int p = 0; p < 4; ++p) {
            __builtin_amdgcn_global_load_lds(
                (const __attribute__((address_space(1))) void*)(A + (size_t)(m0 + p * 32 + grow) * 1024 + k0 + gcol),
                (__attribute__((address_space(3))) void*)(&As[p * 32 + wid * 8][0]), 16, 0, 0);
            __builtin_amdgcn_global_load_lds(
                (const __attribute__((address_space(1))) void*)(Bt + (size_t)(n0 + p * 32 + grow) * 1024 + k0 + gcol),
                (__attribute__((address_space(3))) void*)(&Bs[p * 32 + wid * 8][0]), 16, 0, 0);
        }
        __syncthreads();
#pragma unroll
        for (int kk = 0; kk < 2; ++kk) {
            bf16x8 a[4], b[4];
#pragma unroll
            for (int i = 0; i < 4; ++i) a[i] = *(const bf16x8*)&As[wr * 64 + i * 16 + lm][kk * 32 + lg * 8];
#pragma unroll
            for (int j = 0; j < 4; ++j) b[j] = *(const bf16x8*)&Bs[wc * 64 + j * 16 + lm][kk * 32 + lg * 8];
#pragma unroll
            for (int i = 0; i < 4; ++i)
#pragma unroll
                for (int j = 0; j < 4; ++j) acc[i][j] = MFMA16(a[i], b[j], acc[i][j]);
        }
    }

    for (int i = 0; i < 4; ++i) {
        for (int j = 0; j < 4; ++j) {
            int col = n0 + wc * 64 + j * 16 + lm;
            float bv = bscale * bias[col];
            for (int q = 0; q < 4; ++q) {
                int row = m0 + wr * 64 + i * 16 + lg * 4 + q;
                float val = acc[i][j][q] + bv;
                if (out_mode == 0) {  // bf16 head layout [b][h][s][d]
                    int bb = row >> 11, s = row & 2047, h = col >> 6, d = col & 63;
                    ((bf16*)Cp)[(((size_t)bb * 16 + h) * 2048 + s) * 64 + d] = (bf16)val;
                } else {              // fp32 flat [M][N]
                    ((float*)Cp)[(size_t)row * 1024 + col] = (float)val;
                }
            }
        }
    }
}

// XCD-stripe decode: xcd owns m-tiles 4*xcd..4*xcd+3 (A stripe stays in its L2).
__device__ __forceinline__ void tile_decode(int r, int& m0, int& n0) {
    int xcd = r & 7, slot = (r >> 3) & 3, n = (r >> 5) & 7;
    m0 = (xcd * 4 + slot) * 128;
    n0 = n * 128;
}

__global__ __launch_bounds__(256, 4) void k_gemm_one(const bf16* __restrict__ A,
                                                     const bf16* __restrict__ Bt,
                                                     const float* __restrict__ bias, float bscale,
                                                     void* __restrict__ Cp, int out_mode) {
    __shared__ bf16 As[128][64];
    __shared__ bf16 Bs[128][64];
    int m0, n0;
    tile_decode(blockIdx.x, m0, n0);
    gemm_tile(A, Bt, bias, bscale, Cp, out_mode, m0, n0, As, Bs);
}

// fused Q/K/V projections: grid 768, z selects matrix (3 blocks/CU co-resident)
__global__ __launch_bounds__(256, 4) void k_gemm_qkv(const bf16* __restrict__ qc, const bf16* __restrict__ kc,
                                                     const bf16* __restrict__ vc,
                                                     const bf16* __restrict__ Wtq, const bf16* __restrict__ Wtk,
                                                     const bf16* __restrict__ Wtv,
                                                     const float* __restrict__ bq, const float* __restrict__ bk,
                                                     const float* __restrict__ bv,
                                                     bf16* __restrict__ Qb, bf16* __restrict__ Kb,
                                                     bf16* __restrict__ Vb) {
    __shared__ bf16 As[128][64];
    __shared__ bf16 Bs[128][64];
    int l = blockIdx.x, z = l >> 8, r = l & 255;
    int m0, n0;
    tile_decode(r, m0, n0);
    const bf16* A  = (z == 0) ? qc : ((z == 1) ? kc : vc);
    const bf16* Bt = (z == 0) ? Wtq : ((z == 1) ? Wtk : Wtv);
    const float* bias = (z == 0) ? bq : ((z == 1) ? bk : bv);
    float bscale = (z == 0) ? QSCL : 1.0f;
    bf16* Cp = (z == 0) ? Qb : ((z == 1) ? Kb : Vb);
    gemm_tile(A, Bt, bias, bscale, (void*)Cp, 0, m0, n0, As, Bs);
}

// ---------------- flash attention: zero-LDS, zero-barrier ----------------
// Q,K: [bh][2048][64] bf16 (Q pre-scaled by 0.125*log2e); Vt: [bh][64][2048];
// Out: [b][s][h*64+d] bf16. 8 waves/block, 32 q-rows per wave, KVBLK=64.
// Swapped QK^T (S^T = K·Q^T) and swapped PV (O^T = Vt·P^T): softmax state is lane-local.
__global__ __launch_bounds__(512, 2) void k_attn(const bf16* __restrict__ Q,
                                                 const bf16* __restrict__ Kb,
                                                 const bf16* __restrict__ Vt,
                                                 bf16* __restrict__ Out) {
    const int tid = threadIdx.x;
    const int wid = tid >> 6, lane = tid & 63;
    const int lm = lane & 31, hi = lane >> 5;
    const int bid = blockIdx.x;
    const int bh = bid & 31, qt = bid >> 5;   // same-bh blocks land on one XCD (L2 locality)
    const int bb = bh >> 4, h = bh & 15;
    const int qrow = qt * 256 + wid * 32 + lm;
    const size_t qk_base = (size_t)bh * (2048 * 64);
    const size_t vt_base = (size_t)bh * (64 * 2048);

    // Q fragments (B operand): Q[qrow][f*16 + hi*8 .. +7]
    bf16x8 qf[4];
    {
        const bf16* qp = Q + qk_base + (size_t)qrow * 64 + hi * 8;
#pragma unroll
        for (int f = 0; f < 4; ++f) qf[f] = *(const bf16x8*)(qp + f * 16);
    }

    f32x16 O0 = {}, O1 = {};
    float mrow = -1e30f, lrow = 0.f;

    const bf16* kp  = Kb + qk_base + (size_t)lm * 64 + hi * 8;
    const bf16* vp0 = Vt + vt_base + (size_t)lm * 2048 + hi * 8;
    const bf16* vp1 = Vt + vt_base + (size_t)(32 + lm) * 2048 + hi * 8;

#pragma unroll 1
    for (int kt = 0; kt < 32; ++kt) {
        // K frags (A operand): rows kb*32+lm of tile kt, k-dim = d
        const bf16* kpt = kp + (size_t)kt * 4096;
        bf16x8 kf0[4], kf1[4];
#pragma unroll
        for (int f = 0; f < 4; ++f) {
            kf0[f] = *(const bf16x8*)(kpt + f * 16);
            kf1[f] = *(const bf16x8*)(kpt + 2048 + f * 16);
        }
        // V frags (A operand for O^T): Vt[j*32+lm][kt*64 + ks*16 + hi*8] — issued early, used after softmax
        bf16x8 vf0[4], vf1[4];
#pragma unroll
        for (int ks = 0; ks < 4; ++ks) {
            vf0[ks] = *(const bf16x8*)(vp0 + kt * 64 + ks * 16);
            vf1[ks] = *(const bf16x8*)(vp1 + kt * 64 + ks * 16);
        }

        // S^T = K · Q^T  (col = q = lane&31, row = k-local = (reg&3)+8*(reg>>2)+4*hi)
        f32x16 s0 = {}, s1 = {};
#pragma unroll
        for (int f = 0; f < 4; ++f) {
            s0 = MFMA32(kf0[f], qf[f], s0);
            s1 = MFMA32(kf1[f], qf[f], s1);
        }

        // tile row-max (tree + cross-half swap)
        float t8[8];
#pragma unroll
        for (int r = 0; r < 8; ++r)
            t8[r] = fmaxf(fmaxf(s0[r], s0[r + 8]), fmaxf(s1[r], s1[r + 8]));
#pragma unroll
        for (int st = 4; st; st >>= 1)
#pragma unroll
            for (int r = 0; r < st; ++r) t8[r] = fmaxf(t8[r], t8[r + st]);
        float pm = swapred_max(t8[0]);

        // online rescale every tile (defer-max removed for this A/B round)
        {
            float mnew = fmaxf(mrow, pm);
            float corr = __builtin_amdgcn_exp2f(mrow - mnew);
            lrow *= corr;
            O0 *= corr;
            O1 *= corr;
            mrow = mnew;
        }

        // P = exp2(S - m)
        float p0a[16], p1a[16];
#pragma unroll
        for (int r = 0; r < 16; ++r) p0a[r] = __builtin_amdgcn_exp2f(s0[r] - mrow);
#pragma unroll
        for (int r = 0; r < 16; ++r) p1a[r] = __builtin_amdgcn_exp2f(s1[r] - mrow);
        float u8[8];
#pragma unroll
        for (int r = 0; r < 8; ++r) u8[r] = (p0a[r] + p0a[r + 8]) + (p1a[r] + p1a[r + 8]);
#pragma unroll
        for (int st = 4; st; st >>= 1)
#pragma unroll
            for (int r = 0; r < st; ++r) u8[r] = u8[r] + u8[r + st];
        lrow += swapred_sum(u8[0]);

        // redistribute P into PV B-frags (in-register, shfl_xor 32)
        bf16x8 pf[4];
        pack_frags(p0a, hi, pf[0], pf[1]);
        pack_frags(p1a, hi, pf[2], pf[3]);

        // O^T += Vt · P^T
#pragma unroll
        for (int ks = 0; ks < 4; ++ks) {
            O0 = MFMA32(vf0[ks], pf[ks], O0);
            O1 = MFMA32(vf1[ks], pf[ks], O1);
        }
    }

    float inv = 1.0f / lrow;
    bf16* op = Out + ((size_t)bb * 2048 + qrow) * 1024 + h * 64 + 4 * hi;
#pragma unroll
    for (int t = 0; t < 4; ++t) {
        bf16x4 w0, w1;
#pragma unroll
        for (int e = 0; e < 4; ++e) {
            w0[e] = (bf16)(O0[4 * t + e] * inv);
            w1[e] = (bf16)(O1[4 * t + e] * inv);
        }
        *(bf16x4*)(op + 8 * t)      = w0;   // d = 4*hi + 8*t + e
        *(bf16x4*)(op + 32 + 8 * t) = w1;   // + 32
    }
}

extern "C" void kernel_launch(void* const* d_in, const int* in_sizes, int n_in,
                              void* d_out, int out_size, void* d_ws, size_t ws_size,
                              hipStream_t stream) {
    const float* q  = (const float*)d_in[0];
    const float* k  = (const float*)d_in[1];
    const float* v  = (const float*)d_in[2];
    const float* Wq = (const float*)d_in[3];
    const float* bq = (const float*)d_in[4];
    const float* Wk = (const float*)d_in[5];
    const float* bk = (const float*)d_in[6];
    const float* Wv = (const float*)d_in[7];
    const float* bv = (const float*)d_in[8];
    const float* Wo = (const float*)d_in[9];
    const float* bo = (const float*)d_in[10];

    char* ws = (char*)d_ws;
    const size_t MB = 1ull << 20;
    const dim3 twg(16, 16), blk(256);

    if (ws_size >= 64 * MB) {
        // fused path (64 MB)
        bf16* Wtq = (bf16*)(ws + 0 * MB);
        bf16* Wtk = (bf16*)(ws + 2 * MB);
        bf16* Wtv = (bf16*)(ws + 4 * MB);
        bf16* Wto = (bf16*)(ws + 6 * MB);
        bf16* qc  = (bf16*)(ws + 8 * MB);
        bf16* kc  = (bf16*)(ws + 16 * MB);
        bf16* vc  = (bf16*)(ws + 24 * MB);
        bf16* Qb  = (bf16*)(ws + 32 * MB);
        bf16* Kb  = (bf16*)(ws + 40 * MB);
        bf16* Vb  = (bf16*)(ws + 48 * MB);
        bf16* Vtb = (bf16*)(ws + 56 * MB);
        bf16* AOb = qc;  // qc free after QKV gemm

        k_transpose_w<<<twg, blk, 0, stream>>>(Wq, Wtq, QSCL);
        k_transpose_w<<<twg, blk, 0, stream>>>(Wk, Wtk, 1.0f);
        k_transpose_w<<<twg, blk, 0, stream>>>(Wv, Wtv, 1.0f);
        k_transpose_w<<<twg, blk, 0, stream>>>(Wo, Wto, 1.0f);
        k_cvt3<<<12288, blk, 0, stream>>>(q, k, v, qc, kc, vc);
        k_gemm_qkv<<<768, blk, 0, stream>>>(qc, kc, vc, Wtq, Wtk, Wtv, bq, bk, bv, Qb, Kb, Vb);
        k_transpose_v<<<dim3(32, 32), blk, 0, stream>>>(Vb, Vtb);
        k_attn<<<256, 512, 0, stream>>>(Qb, Kb, Vtb, AOb);
        k_gemm_one<<<256, blk, 0, stream>>>(AOb, Wto, bo, 1.0f, d_out, 1);
    } else {
        // sequential fallback (34 MB, proven in round 1)
        bf16* Wt  = (bf16*)(ws + 0 * MB);
        bf16* Qb  = (bf16*)(ws + 2 * MB);
        bf16* Kb  = (bf16*)(ws + 10 * MB);
        bf16* Vb  = (bf16*)(ws + 18 * MB);
        bf16* Vtb = (bf16*)(ws + 26 * MB);
        bf16* Cb  = Vtb;   // cvt scratch until transpose_v
        bf16* AOb = Vb;

        k_cvt1<<<4096, blk, 0, stream>>>(q, Cb);
        k_transpose_w<<<twg, blk, 0, stream>>>(Wq, Wt, QSCL);
        k_gemm_one<<<256, blk, 0, stream>>>(Cb, Wt, bq, QSCL, (void*)Qb, 0);
        k_cvt1<<<4096, blk, 0, stream>>>(k, Cb);
        k_transpose_w<<<twg, blk, 0, stream>>>(Wk, Wt, 1.0f);
        k_gemm_one<<<256, blk, 0, stream>>>(Cb, Wt, bk, 1.0f, (void*)Kb, 0);
        k_cvt1<<<4096, blk, 0, stream>>>(v, Cb);
        k_transpose_w<<<twg, blk, 0, stream>>>(Wv, Wt, 1.0f);
        k_gemm_one<<<256, blk, 0, stream>>>(Cb, Wt, bv, 1.0f, (void*)Vb, 0);
        k_transpose_v<<<dim3(32, 32), blk, 0, stream>>>(Vb, Vtb);
        k_transpose_w<<<twg, blk, 0, stream>>>(Wo, Wt, 1.0f);
        k_attn<<<256, 512, 0, stream>>>(Qb, Kb, Vtb, AOb);
        k_gemm_one<<<256, blk, 0, stream>>>(AOb, Wt, bo, 1.0f, d_out, 1);
    }
}